// Round 1
// baseline (409.937 us; speedup 1.0000x reference)
//
#include <hip/hip_runtime.h>
#include <hip/hip_bf16.h>
#include <math.h>
#include <stdint.h>

// ---------------- types & helpers ----------------
typedef __attribute__((ext_vector_type(8))) short short8;   // 8 x bf16 (MFMA A/B frag)
typedef __attribute__((ext_vector_type(4))) float floatx4;  // MFMA C/D frag

#define DEVI __device__ __forceinline__

DEVI float b2f(unsigned short u) {
    union { unsigned int i; float f; } v; v.i = ((unsigned int)u) << 16; return v.f;
}
DEVI unsigned short f2b(float f) {   // RNE f32 -> bf16
    unsigned int x = __float_as_uint(f);
    unsigned int r = (x + 0x7fffu + ((x >> 16) & 1u)) >> 16;
    return (unsigned short)r;
}

// global -> LDS direct (16B per lane). LDS dest must be wave-uniform base + lane*16.
#define GLD16(gp, lp)                                                            \
    __builtin_amdgcn_global_load_lds(                                            \
        (__attribute__((address_space(1))) unsigned int*)(gp),                   \
        (__attribute__((address_space(3))) unsigned int*)(lp), 16, 0, 0)

static constexpr int NQ = 4096, NS = 16384;
static constexpr int NROW_Q = 4 * NQ;   // 16384 query rows
static constexpr int NROW_S = 4 * NS;   // 65536 source rows
static constexpr float INV2PI = 0.15915494309189535f;

// ---------------- prep: transpose weights to bf16 [N][K], penc0 ----------------
__global__ void k_prep(const float* Wproj, const float* saWv, const float* saWo,
                       const float* caWq, const float* caWk, const float* caWv,
                       const float* caWo, const float* W1, const float* W2,
                       const float* b_pos,
                       unsigned short* wTproj, unsigned short* wTsaWv, unsigned short* wTsaWo,
                       unsigned short* wTcaWq, unsigned short* wTkv, unsigned short* wTcaWo,
                       unsigned short* wTW1, unsigned short* wTW2, float* penc0)
{
    int z = blockIdx.z;
    if (z == 9) {   // penc0[c] = pos_enc(0): [0,0,0, cos(b_pos)]
        if (blockIdx.x == 0 && blockIdx.y == 0) {
            int c = threadIdx.y * 16 + threadIdx.x;
            float v = 0.f;
            if (c >= 3) {
                float rev = b_pos[c - 3] * INV2PI;
                rev -= floorf(rev);
                v = __builtin_amdgcn_cosf(rev);
            }
            penc0[c] = v;
        }
        return;
    }
    int n = blockIdx.x * 16 + threadIdx.x;   // output row (orig col)
    int k = blockIdx.y * 16 + threadIdx.y;   // output col (orig row)
    const float* src; unsigned short* dst; int K = 256;
    switch (z) {
        case 0: src = Wproj; dst = wTproj; K = 128; break;
        case 1: src = saWv;  dst = wTsaWv; break;
        case 2: src = saWo;  dst = wTsaWo; break;
        case 3: src = caWq;  dst = wTcaWq; break;
        case 4: src = caWk;  dst = wTkv;   break;
        case 5: src = caWv;  dst = wTkv + 256 * 256; break;
        case 6: src = caWo;  dst = wTcaWo; break;
        case 7: src = W1;    dst = wTW1;   break;
        default: src = W2;   dst = wTW2;   break;
    }
    if (k < K) dst[(size_t)n * K + k] = f2b(src[(size_t)k * 256 + n]);
}

// ---------------- f32 -> bf16 convert ----------------
__global__ void k_cvt(const float* in, unsigned short* out, int n4)
{
    int i = blockIdx.x * blockDim.x + threadIdx.x;
    int stride = gridDim.x * blockDim.x;
    for (; i < n4; i += stride) {
        float4 v = ((const float4*)in)[i];
        unsigned long long p =
              (unsigned long long)f2b(v.x)
            | ((unsigned long long)f2b(v.y) << 16)
            | ((unsigned long long)f2b(v.z) << 32)
            | ((unsigned long long)f2b(v.w) << 48);
        ((unsigned long long*)out)[i] = p;
    }
}

// ---------------- MFMA GEMM: out[M][N] = A[M][K](bf16) @ BT[N][K]^T + epilogue ----------------
// EPI: 0 = bf16 out, +bias            1 = bf16 out, +bias, relu
//      2 = f32 out, +bias +extra[col] 3 = f32 out, +bias +extra[row,col]
//      4 = f32 out, +bias +extra[row,col], nan_to_num
template<int EPI>
__global__ __launch_bounds__(256, 2)
void k_gemm(const unsigned short* A, const unsigned short* BT, const float* bias,
            const float* extra, void* outp, int M, int N, int K)
{
    __shared__ alignas(16) unsigned short lA[128 * 64];  // [128 rows][64 k], swizzled
    __shared__ alignas(16) unsigned short lB[64 * 64];   // [64 rows][64 k], swizzled
    const int tid = threadIdx.x;
    const int wave = tid >> 6, lane = tid & 63;
    const int m0 = blockIdx.x * 128, n0 = blockIdx.y * 64;
    const int wm = (wave >> 1) * 64, wn = (wave & 1) * 32;
    floatx4 acc[4][2] = {};

    for (int kt = 0; kt < K; kt += 64) {
        __syncthreads();
        #pragma unroll
        for (int c = 0; c < 4; ++c) {   // stage A tile 16KB
            int o = (tid + c * 256) * 16;
            int row = o >> 7, inner = o & 127;
            int srk = inner ^ ((row & 7) << 4);
            GLD16((const char*)A + ((size_t)(m0 + row) * K + kt) * 2 + srk, (char*)lA + o);
        }
        #pragma unroll
        for (int c = 0; c < 2; ++c) {   // stage B tile 8KB
            int o = (tid + c * 256) * 16;
            int row = o >> 7, inner = o & 127;
            int srk = inner ^ ((row & 7) << 4);
            GLD16((const char*)BT + ((size_t)(n0 + row) * K + kt) * 2 + srk, (char*)lB + o);
        }
        __syncthreads();
        #pragma unroll
        for (int kc = 0; kc < 2; ++kc) {
            const int kb = kc * 64 + ((lane >> 4) << 4);
            short8 bf[2];
            #pragma unroll
            for (int nf = 0; nf < 2; ++nf) {
                int nn = wn + nf * 16 + (lane & 15);
                bf[nf] = *(const short8*)((const char*)lB + nn * 128 + (kb ^ ((nn & 7) << 4)));
            }
            #pragma unroll
            for (int mf = 0; mf < 4; ++mf) {
                int rr = wm + mf * 16 + (lane & 15);
                short8 af = *(const short8*)((const char*)lA + rr * 128 + (kb ^ ((rr & 7) << 4)));
                acc[mf][0] = __builtin_amdgcn_mfma_f32_16x16x32_bf16(af, bf[0], acc[mf][0], 0, 0, 0);
                acc[mf][1] = __builtin_amdgcn_mfma_f32_16x16x32_bf16(af, bf[1], acc[mf][1], 0, 0, 0);
            }
        }
    }
    #pragma unroll
    for (int mf = 0; mf < 4; ++mf)
        #pragma unroll
        for (int nf = 0; nf < 2; ++nf)
            #pragma unroll
            for (int r = 0; r < 4; ++r) {
                int row = m0 + wm + mf * 16 + ((lane >> 4) << 2) + r;
                int col = n0 + wn + nf * 16 + (lane & 15);
                float v = acc[mf][nf][r] + bias[col];
                if (EPI == 2) v += extra[col];
                if (EPI == 3 || EPI == 4) v += extra[(size_t)row * N + col];
                if (EPI == 1) v = fmaxf(v, 0.f);
                if (EPI == 4) {
                    if (isnan(v)) v = 0.f;
                    else if (isinf(v)) v = v > 0.f ? 3.402823466e38f : -3.402823466e38f;
                }
                if (EPI == 0 || EPI == 1)
                    ((unsigned short*)outp)[(size_t)row * N + col] = f2b(v);
                else
                    ((float*)outp)[(size_t)row * N + col] = v;
            }
}

// ---------------- LayerNorm (f32 in, bf16 out), one wave per 256-row ----------------
__global__ __launch_bounds__(256, 2)
void k_ln(const float* x, const float* g, const float* b, unsigned short* out)
{
    int row = blockIdx.x * 4 + (threadIdx.x >> 6);
    int lane = threadIdx.x & 63;
    const float* xr = x + (size_t)row * 256;
    float4 v = ((const float4*)xr)[lane];
    float s = v.x + v.y + v.z + v.w;
    #pragma unroll
    for (int t = 32; t >= 1; t >>= 1) s += __shfl_xor(s, t, 64);
    float mean = s * (1.f / 256.f);
    float d0 = v.x - mean, d1 = v.y - mean, d2 = v.z - mean, d3 = v.w - mean;
    float q = d0 * d0 + d1 * d1 + d2 * d2 + d3 * d3;
    #pragma unroll
    for (int t = 32; t >= 1; t >>= 1) q += __shfl_xor(q, t, 64);
    float inv = 1.0f / sqrtf(q * (1.f / 256.f) + 1e-5f);
    int c = lane * 4;
    unsigned long long p =
          (unsigned long long)f2b(d0 * inv * g[c] + b[c])
        | ((unsigned long long)f2b(d1 * inv * g[c + 1] + b[c + 1]) << 16)
        | ((unsigned long long)f2b(d2 * inv * g[c + 2] + b[c + 2]) << 32)
        | ((unsigned long long)f2b(d3 * inv * g[c + 3] + b[c + 3]) << 48);
    ((unsigned long long*)(out + (size_t)row * 256))[lane] = p;
}

// ---------------- fused neighbor attention ----------------
// block = 8 queries (128 neighbor rows), 512 threads (8 waves).
// P1: gather src_p + pos-enc -> nx LDS (bf16, swizzled)
// P2: kk = nx @ Wk (pass0), vv = nx @ Wv (pass1), MFMA, results -> LDS bf16
// P4: per-wave (per-query) masked softmax over 16 neighbors + context, +bv, -> ctx
__global__ __launch_bounds__(512, 2)
void k_attn(const unsigned short* srcp, const unsigned short* qb, const int* inds,
            const float* s_pts, const float* q_pts, const float* W_pos, const float* b_pos,
            const unsigned short* wTkv, const float* bv, unsigned short* ctx)
{
    __shared__ alignas(1024) char lds[151552];
    unsigned short* nx  = (unsigned short*)lds;             // [128][256] swizzled, [0,65536)
    unsigned short* kkL = (unsigned short*)(lds + 67584);   // [128][264]
    unsigned short* vvL = (unsigned short*)lds;             // [128][264] (over nx, after it dies)
    char* bst0 = lds + 67584;    // pass0 B stage [256][32] (dies before kk write)
    char* bst1 = lds + 135168;   // pass1 B stage [256][32]
    const int tid = threadIdx.x, wave = tid >> 6, lane = tid & 63;
    const int qbase = blockIdx.x * 8;

    // ---- P1: gather + positional encoding ----
    {
        int r = tid >> 2, sub = tid & 3;          // row 0..127, 64-col chunk
        int qi = qbase + (r >> 4);
        int bb = qi >> 12;                        // / NQ
        int k = r & 15;
        int raw = inds[((size_t)qi << 4) + k];
        int idx = raw % (NS + 1); if (idx < 0) idx += NS + 1;
        float px = q_pts[(size_t)qi * 3], py = q_pts[(size_t)qi * 3 + 1], pz = q_pts[(size_t)qi * 3 + 2];
        bool shadow = (idx == NS);
        float sx, sy, sz;
        const unsigned short* srow = srcp;
        if (shadow) { sx = sy = sz = 1e6f; }
        else {
            const float* sp = s_pts + ((size_t)bb * NS + idx) * 3;
            sx = sp[0]; sy = sp[1]; sz = sp[2];
            srow = srcp + ((size_t)bb * NS + idx) * 256;
        }
        float tx = (sx - px) * 0.25f, ty = (sy - py) * 0.25f, tz = (sz - pz) * 0.25f;
        const int c0 = sub * 64;
        for (int cc = 0; cc < 64; cc += 8) {
            short8 sv = {0, 0, 0, 0, 0, 0, 0, 0};
            if (!shadow) sv = *(const short8*)(srow + c0 + cc);
            short8 vals;
            #pragma unroll
            for (int j = 0; j < 8; ++j) {
                int c = c0 + cc + j;
                float pe;
                if (c == 0) pe = tx;
                else if (c == 1) pe = ty;
                else if (c == 2) pe = tz;
                else {
                    int jj = c - 3;
                    float rev = fmaf(tx, W_pos[jj],
                                fmaf(ty, W_pos[253 + jj],
                                fmaf(tz, W_pos[506 + jj], b_pos[jj] * INV2PI)));
                    rev -= floorf(rev);
                    pe = __builtin_amdgcn_cosf(rev);
                }
                float sval = shadow ? 0.f : b2f((unsigned short)sv[j]);
                vals[j] = (short)f2b(sval + pe);
            }
            int byte = (c0 + cc) * 2;
            *(short8*)((char*)nx + r * 512 + (byte ^ ((r & 7) << 4))) = vals;
        }
    }
    __syncthreads();

    // ---- P2: kk/vv = nx @ {Wk,Wv} ----
    const int wm = (wave >> 2) * 64;
    const int wn = (wave & 3) * 64;
    #pragma unroll 1
    for (int pass = 0; pass < 2; ++pass) {
        char* bs = pass ? bst1 : bst0;
        floatx4 acc[4][4] = {};
        #pragma unroll 1
        for (int kt = 0; kt < 8; ++kt) {          // 8 chunks of 32 k
            __syncthreads();
            #pragma unroll
            for (int c = 0; c < 2; ++c) {         // stage B [256 n][32 k] = 16KB
                int o = (tid + c * 512) * 16;
                int row = o >> 6, inner = o & 63;
                int srk = inner ^ ((row & 3) << 4);
                GLD16((const char*)wTkv + ((size_t)(pass * 256 + row)) * 512 + kt * 64 + srk, bs + o);
            }
            __syncthreads();
            const int kb = (lane >> 4) << 4;
            short8 bfr[4];
            #pragma unroll
            for (int nf = 0; nf < 4; ++nf) {
                int nn = wn + nf * 16 + (lane & 15);
                bfr[nf] = *(const short8*)(bs + nn * 64 + (kb ^ ((nn & 3) << 4)));
            }
            #pragma unroll
            for (int mf = 0; mf < 4; ++mf) {
                int rr = wm + mf * 16 + (lane & 15);
                short8 af = *(const short8*)((const char*)nx + rr * 512 + ((kt * 64 + kb) ^ ((rr & 7) << 4)));
                #pragma unroll
                for (int nf = 0; nf < 4; ++nf)
                    acc[mf][nf] = __builtin_amdgcn_mfma_f32_16x16x32_bf16(af, bfr[nf], acc[mf][nf], 0, 0, 0);
            }
        }
        __syncthreads();
        unsigned short* dst = pass ? vvL : kkL;
        #pragma unroll
        for (int mf = 0; mf < 4; ++mf)
            #pragma unroll
            for (int nf = 0; nf < 4; ++nf)
                #pragma unroll
                for (int r = 0; r < 4; ++r) {
                    int row = wm + mf * 16 + ((lane >> 4) << 2) + r;
                    int col = wn + nf * 16 + (lane & 15);
                    dst[row * 264 + col] = f2b(acc[mf][nf][r]);
                }
    }
    __syncthreads();

    // ---- P4: per-query attention (wave w -> query qbase+w) ----
    {
        int qi = qbase + wave;
        int bb = qi >> 12;
        int s = lane & 15, g = lane >> 4;
        // recompute mask for neighbor k = s
        int raw = inds[((size_t)qi << 4) + s];
        int idx = raw % (NS + 1); if (idx < 0) idx += NS + 1;
        float px = q_pts[(size_t)qi * 3], py = q_pts[(size_t)qi * 3 + 1], pz = q_pts[(size_t)qi * 3 + 2];
        float sx, sy, sz;
        if (idx == NS) { sx = sy = sz = 1e6f; }
        else { const float* sp = s_pts + ((size_t)bb * NS + idx) * 3; sx = sp[0]; sy = sp[1]; sz = sp[2]; }
        float dx = sx - px, dy = sy - py, dz = sz - pz;
        bool masked = sqrtf(dx * dx + dy * dy + dz * dz) > 4.0f;

        const unsigned short* qrow = qb + (size_t)qi * 256;
        float attv[4];
        #pragma unroll
        for (int i = 0; i < 4; ++i) {
            int h = g * 4 + i;
            const unsigned short* kr = kkL + ((size_t)(wave * 16 + s)) * 264 + h * 16;
            short8 k0 = *(const short8*)kr;
            short8 k1 = *(const short8*)(kr + 8);
            short8 q0 = *(const short8*)(qrow + h * 16);
            short8 q1 = *(const short8*)(qrow + h * 16 + 8);
            float sc = 0.f;
            #pragma unroll
            for (int d = 0; d < 8; ++d) {
                sc = fmaf(b2f((unsigned short)q0[d]), b2f((unsigned short)k0[d]), sc);
                sc = fmaf(b2f((unsigned short)q1[d]), b2f((unsigned short)k1[d]), sc);
            }
            sc *= 0.25f;                  // / sqrt(HD)
            if (masked) sc = -1e9f;       // replace (exact reference semantics)
            float m = sc;
            #pragma unroll
            for (int t = 8; t >= 1; t >>= 1) m = fmaxf(m, __shfl_xor(m, t, 16));
            float p = __expf(sc - m);     // all-masked -> p=1 -> uniform 1/16
            float su = p;
            #pragma unroll
            for (int t = 8; t >= 1; t >>= 1) su += __shfl_xor(su, t, 16);
            attv[i] = p / su;
        }
        int d = s;
        #pragma unroll
        for (int i = 0; i < 4; ++i) {
            int h = g * 4 + i;
            float o = 0.f;
            #pragma unroll
            for (int k2 = 0; k2 < 16; ++k2) {
                float a = __shfl(attv[i], (lane & 48) + k2, 64);
                o = fmaf(a, b2f(vvL[((size_t)(wave * 16 + k2)) * 264 + h * 16 + d]), o);
            }
            o += bv[h * 16 + d];          // Σatt==1 → add bias once
            ctx[(size_t)qi * 256 + h * 16 + d] = f2b(o);
        }
    }
}

// ---------------- host launcher ----------------
extern "C" void kernel_launch(void* const* d_in, const int* in_sizes, int n_in,
                              void* d_out, int out_size, void* d_ws, size_t ws_size,
                              hipStream_t stream)
{
    const float* q_pts   = (const float*)d_in[0];
    const float* s_pts   = (const float*)d_in[1];
    const float* src_f   = (const float*)d_in[2];
    const float* query_f = (const float*)d_in[3];
    const float* W_proj  = (const float*)d_in[4];
    const float* b_proj  = (const float*)d_in[5];
    const float* W_pos   = (const float*)d_in[6];
    const float* b_pos   = (const float*)d_in[7];
    const float* ln1_g   = (const float*)d_in[8];
    const float* ln1_b   = (const float*)d_in[9];
    const float* sa_Wv   = (const float*)d_in[10];
    const float* sa_bv   = (const float*)d_in[11];
    const float* sa_Wo   = (const float*)d_in[12];
    const float* sa_bo   = (const float*)d_in[13];
    const float* ln2_g   = (const float*)d_in[14];
    const float* ln2_b   = (const float*)d_in[15];
    const float* ca_Wq   = (const float*)d_in[16];
    const float* ca_bq   = (const float*)d_in[17];
    const float* ca_Wk   = (const float*)d_in[18];
    /* ca_bk = d_in[19] unused: softmax shift-invariant */
    const float* ca_Wv   = (const float*)d_in[20];
    const float* ca_bv   = (const float*)d_in[21];
    const float* ca_Wo   = (const float*)d_in[22];
    const float* ca_bo   = (const float*)d_in[23];
    const float* ln3_g   = (const float*)d_in[24];
    const float* ln3_b   = (const float*)d_in[25];
    const float* W1      = (const float*)d_in[26];
    const float* b1      = (const float*)d_in[27];
    const float* W2      = (const float*)d_in[28];
    const float* b2      = (const float*)d_in[29];
    const int*   inds    = (const int*)d_in[30];

    char* ws = (char*)d_ws;
    size_t off = 0;
    auto alloc = [&](size_t bytes) { char* p = ws + off; off += (bytes + 1023) & ~(size_t)1023; return p; };

    unsigned short* wTproj = (unsigned short*)alloc(256 * 128 * 2);
    unsigned short* wTsaWv = (unsigned short*)alloc(256 * 256 * 2);
    unsigned short* wTsaWo = (unsigned short*)alloc(256 * 256 * 2);
    unsigned short* wTcaWq = (unsigned short*)alloc(256 * 256 * 2);
    unsigned short* wTkv   = (unsigned short*)alloc(512 * 256 * 2);
    unsigned short* wTcaWo = (unsigned short*)alloc(256 * 256 * 2);
    unsigned short* wTW1   = (unsigned short*)alloc(256 * 256 * 2);
    unsigned short* wTW2   = (unsigned short*)alloc(256 * 256 * 2);
    float*          penc0  = (float*)alloc(256 * 4);
    unsigned short* srcb   = (unsigned short*)alloc((size_t)NROW_S * 128 * 2);
    unsigned short* qfb    = (unsigned short*)alloc((size_t)NROW_Q * 128 * 2);
    unsigned short* srcp   = (unsigned short*)alloc((size_t)NROW_S * 256 * 2);
    float*          qx     = (float*)alloc((size_t)NROW_Q * 256 * 4);
    unsigned short* hbuf   = (unsigned short*)alloc((size_t)NROW_Q * 256 * 2);
    unsigned short* tbuf   = (unsigned short*)alloc((size_t)NROW_Q * 256 * 2);
    float*          xbuf   = (float*)alloc((size_t)NROW_Q * 256 * 4);
    unsigned short* qbuf   = (unsigned short*)alloc((size_t)NROW_Q * 256 * 2);
    unsigned short* ctxbuf = (unsigned short*)alloc((size_t)NROW_Q * 256 * 2);
    float*          x2buf  = (float*)alloc((size_t)NROW_Q * 256 * 4);

    dim3 bl16(16, 16);
    k_prep<<<dim3(16, 16, 10), bl16, 0, stream>>>(
        W_proj, sa_Wv, sa_Wo, ca_Wq, ca_Wk, ca_Wv, ca_Wo, W1, W2, b_pos,
        wTproj, wTsaWv, wTsaWo, wTcaWq, wTkv, wTcaWo, wTW1, wTW2, penc0);

    k_cvt<<<1024, 256, 0, stream>>>(src_f, srcb, NROW_S * 128 / 4);
    k_cvt<<<1024, 256, 0, stream>>>(query_f, qfb, NROW_Q * 128 / 4);

    // src_p = src @ W_proj + b_proj  (bf16)
    k_gemm<0><<<dim3(512, 4), 256, 0, stream>>>(srcb, wTproj, b_proj, nullptr, srcp, NROW_S, 256, 128);
    // query_x = query @ W_proj + b_proj + pos_enc(0)  (f32 master)
    k_gemm<2><<<dim3(128, 4), 256, 0, stream>>>(qfb, wTproj, b_proj, penc0, qx, NROW_Q, 256, 128);

    // self-attention block (seq len 1): x = qx + (ln1(qx)@saWv+bv)@saWo+bo
    k_ln<<<4096, 256, 0, stream>>>(qx, ln1_g, ln1_b, hbuf);
    k_gemm<0><<<dim3(128, 4), 256, 0, stream>>>(hbuf, wTsaWv, sa_bv, nullptr, tbuf, NROW_Q, 256, 256);
    k_gemm<3><<<dim3(128, 4), 256, 0, stream>>>(tbuf, wTsaWo, sa_bo, qx, xbuf, NROW_Q, 256, 256);

    // cross-attention
    k_ln<<<4096, 256, 0, stream>>>(xbuf, ln2_g, ln2_b, hbuf);
    k_gemm<0><<<dim3(128, 4), 256, 0, stream>>>(hbuf, wTcaWq, ca_bq, nullptr, qbuf, NROW_Q, 256, 256);
    k_attn<<<2048, 512, 0, stream>>>(srcp, qbuf, inds, s_pts, q_pts, W_pos, b_pos, wTkv, ca_bv, ctxbuf);
    k_gemm<3><<<dim3(128, 4), 256, 0, stream>>>(ctxbuf, wTcaWo, ca_bo, xbuf, x2buf, NROW_Q, 256, 256);

    // feed-forward + nan_to_num -> d_out (f32)
    k_ln<<<4096, 256, 0, stream>>>(x2buf, ln3_g, ln3_b, hbuf);
    k_gemm<1><<<dim3(128, 4), 256, 0, stream>>>(hbuf, wTW1, b1, nullptr, tbuf, NROW_Q, 256, 256);
    k_gemm<4><<<dim3(128, 4), 256, 0, stream>>>(tbuf, wTW2, b2, x2buf, d_out, NROW_Q, 256, 256);

    (void)in_sizes; (void)n_in; (void)out_size; (void)ws_size;
}

// Round 2
// 398.190 us; speedup vs baseline: 1.0295x; 1.0295x over previous
//
#include <hip/hip_runtime.h>
#include <hip/hip_bf16.h>
#include <math.h>
#include <stdint.h>

// ---------------- types & helpers ----------------
typedef __attribute__((ext_vector_type(8))) short short8;   // 8 x bf16 (MFMA A/B frag)
typedef __attribute__((ext_vector_type(4))) float floatx4;  // MFMA C/D frag

#define DEVI __device__ __forceinline__

DEVI float b2f(unsigned short u) {
    union { unsigned int i; float f; } v; v.i = ((unsigned int)u) << 16; return v.f;
}
DEVI unsigned short f2b(float f) {   // RNE f32 -> bf16
    unsigned int x = __float_as_uint(f);
    unsigned int r = (x + 0x7fffu + ((x >> 16) & 1u)) >> 16;
    return (unsigned short)r;
}

// global -> LDS direct (16B per lane). LDS dest must be wave-uniform base + lane*16.
#define GLD16(gp, lp)                                                            \
    __builtin_amdgcn_global_load_lds(                                            \
        (__attribute__((address_space(1))) unsigned int*)(gp),                   \
        (__attribute__((address_space(3))) unsigned int*)(lp), 16, 0, 0)

static constexpr int NQ = 4096, NS = 16384;
static constexpr int NROW_Q = 4 * NQ;   // 16384 query rows
static constexpr int NROW_S = 4 * NS;   // 65536 source rows
static constexpr float INV2PI = 0.15915494309189535f;

// ---------------- prep: transpose weights to bf16 [N][K], penc0 ----------------
__global__ void k_prep(const float* Wproj, const float* saWv, const float* saWo,
                       const float* caWq, const float* caWk, const float* caWv,
                       const float* caWo, const float* W1, const float* W2,
                       const float* b_pos,
                       unsigned short* wTproj, unsigned short* wTsaWv, unsigned short* wTsaWo,
                       unsigned short* wTcaWq, unsigned short* wTkv, unsigned short* wTcaWo,
                       unsigned short* wTW1, unsigned short* wTW2, float* penc0)
{
    int z = blockIdx.z;
    if (z == 9) {   // penc0[c] = pos_enc(0): [0,0,0, cos(b_pos)]
        if (blockIdx.x == 0 && blockIdx.y == 0) {
            int c = threadIdx.y * 16 + threadIdx.x;
            float v = 0.f;
            if (c >= 3) {
                float rev = b_pos[c - 3] * INV2PI;
                rev -= floorf(rev);
                v = __builtin_amdgcn_cosf(rev);
            }
            penc0[c] = v;
        }
        return;
    }
    int n = blockIdx.x * 16 + threadIdx.x;   // output row (orig col)
    int k = blockIdx.y * 16 + threadIdx.y;   // output col (orig row)
    const float* src; unsigned short* dst; int K = 256;
    switch (z) {
        case 0: src = Wproj; dst = wTproj; K = 128; break;
        case 1: src = saWv;  dst = wTsaWv; break;
        case 2: src = saWo;  dst = wTsaWo; break;
        case 3: src = caWq;  dst = wTcaWq; break;
        case 4: src = caWk;  dst = wTkv;   break;
        case 5: src = caWv;  dst = wTkv + 256 * 256; break;
        case 6: src = caWo;  dst = wTcaWo; break;
        case 7: src = W1;    dst = wTW1;   break;
        default: src = W2;   dst = wTW2;   break;
    }
    if (k < K) dst[(size_t)n * K + k] = f2b(src[(size_t)k * 256 + n]);
}

// ---------------- f32 -> bf16 convert ----------------
__global__ void k_cvt(const float* in, unsigned short* out, int n4)
{
    int i = blockIdx.x * blockDim.x + threadIdx.x;
    int stride = gridDim.x * blockDim.x;
    for (; i < n4; i += stride) {
        float4 v = ((const float4*)in)[i];
        unsigned long long p =
              (unsigned long long)f2b(v.x)
            | ((unsigned long long)f2b(v.y) << 16)
            | ((unsigned long long)f2b(v.z) << 32)
            | ((unsigned long long)f2b(v.w) << 48);
        ((unsigned long long*)out)[i] = p;
    }
}

// ---------------- MFMA GEMM: out[M][N] = A[M][K](bf16) @ BT[N][K]^T + epilogue ----------------
// EPI: 0 = bf16 out, +bias            1 = bf16 out, +bias, relu
//      2 = f32 out, +bias +extra[col] 3 = f32 out, +bias +extra[row,col]
//      4 = f32 out, +bias +extra[row,col], nan_to_num
template<int EPI>
__global__ __launch_bounds__(256, 2)
void k_gemm(const unsigned short* A, const unsigned short* BT, const float* bias,
            const float* extra, void* outp, int M, int N, int K)
{
    __shared__ alignas(16) unsigned short lA[128 * 64];  // [128 rows][64 k], swizzled
    __shared__ alignas(16) unsigned short lB[64 * 64];   // [64 rows][64 k], swizzled
    const int tid = threadIdx.x;
    const int wave = tid >> 6, lane = tid & 63;
    const int m0 = blockIdx.x * 128, n0 = blockIdx.y * 64;
    const int wm = (wave >> 1) * 64, wn = (wave & 1) * 32;
    floatx4 acc[4][2] = {};

    for (int kt = 0; kt < K; kt += 64) {
        __syncthreads();
        #pragma unroll
        for (int c = 0; c < 4; ++c) {   // stage A tile 16KB
            int o = (tid + c * 256) * 16;
            int row = o >> 7, inner = o & 127;
            int srk = inner ^ ((row & 7) << 4);
            GLD16((const char*)A + ((size_t)(m0 + row) * K + kt) * 2 + srk, (char*)lA + o);
        }
        #pragma unroll
        for (int c = 0; c < 2; ++c) {   // stage B tile 8KB
            int o = (tid + c * 256) * 16;
            int row = o >> 7, inner = o & 127;
            int srk = inner ^ ((row & 7) << 4);
            GLD16((const char*)BT + ((size_t)(n0 + row) * K + kt) * 2 + srk, (char*)lB + o);
        }
        __syncthreads();
        #pragma unroll
        for (int kc = 0; kc < 2; ++kc) {
            const int kb = kc * 64 + ((lane >> 4) << 4);
            short8 bf[2];
            #pragma unroll
            for (int nf = 0; nf < 2; ++nf) {
                int nn = wn + nf * 16 + (lane & 15);
                bf[nf] = *(const short8*)((const char*)lB + nn * 128 + (kb ^ ((nn & 7) << 4)));
            }
            #pragma unroll
            for (int mf = 0; mf < 4; ++mf) {
                int rr = wm + mf * 16 + (lane & 15);
                short8 af = *(const short8*)((const char*)lA + rr * 128 + (kb ^ ((rr & 7) << 4)));
                acc[mf][0] = __builtin_amdgcn_mfma_f32_16x16x32_bf16(af, bf[0], acc[mf][0], 0, 0, 0);
                acc[mf][1] = __builtin_amdgcn_mfma_f32_16x16x32_bf16(af, bf[1], acc[mf][1], 0, 0, 0);
            }
        }
    }
    #pragma unroll
    for (int mf = 0; mf < 4; ++mf)
        #pragma unroll
        for (int nf = 0; nf < 2; ++nf)
            #pragma unroll
            for (int r = 0; r < 4; ++r) {
                int row = m0 + wm + mf * 16 + ((lane >> 4) << 2) + r;
                int col = n0 + wn + nf * 16 + (lane & 15);
                float v = acc[mf][nf][r] + bias[col];
                if (EPI == 2) v += extra[col];
                if (EPI == 3 || EPI == 4) v += extra[(size_t)row * N + col];
                if (EPI == 1) v = fmaxf(v, 0.f);
                if (EPI == 4) {
                    if (isnan(v)) v = 0.f;
                    else if (isinf(v)) v = v > 0.f ? 3.402823466e38f : -3.402823466e38f;
                }
                if (EPI == 0 || EPI == 1)
                    ((unsigned short*)outp)[(size_t)row * N + col] = f2b(v);
                else
                    ((float*)outp)[(size_t)row * N + col] = v;
            }
}

// ---------------- LayerNorm (f32 in, bf16 out), one wave per 256-row ----------------
__global__ __launch_bounds__(256, 2)
void k_ln(const float* x, const float* g, const float* b, unsigned short* out)
{
    int row = blockIdx.x * 4 + (threadIdx.x >> 6);
    int lane = threadIdx.x & 63;
    const float* xr = x + (size_t)row * 256;
    float4 v = ((const float4*)xr)[lane];
    float s = v.x + v.y + v.z + v.w;
    #pragma unroll
    for (int t = 32; t >= 1; t >>= 1) s += __shfl_xor(s, t, 64);
    float mean = s * (1.f / 256.f);
    float d0 = v.x - mean, d1 = v.y - mean, d2 = v.z - mean, d3 = v.w - mean;
    float q = d0 * d0 + d1 * d1 + d2 * d2 + d3 * d3;
    #pragma unroll
    for (int t = 32; t >= 1; t >>= 1) q += __shfl_xor(q, t, 64);
    float inv = 1.0f / sqrtf(q * (1.f / 256.f) + 1e-5f);
    int c = lane * 4;
    unsigned long long p =
          (unsigned long long)f2b(d0 * inv * g[c] + b[c])
        | ((unsigned long long)f2b(d1 * inv * g[c + 1] + b[c + 1]) << 16)
        | ((unsigned long long)f2b(d2 * inv * g[c + 2] + b[c + 2]) << 32)
        | ((unsigned long long)f2b(d3 * inv * g[c + 3] + b[c + 3]) << 48);
    ((unsigned long long*)(out + (size_t)row * 256))[lane] = p;
}

// ---------------- fused neighbor attention (register-resident) ----------------
// block = 4 queries (64 neighbor rows), 256 threads (4 waves). 4 blocks/CU.
// P1: gather src_p + pos-enc -> nx LDS (bf16, swizzled) + dist2 -> LDS. ONE barrier.
// P2: kk = nx @ Wk, acc in regs (wave w: all 64 rows x heads 4w..4w+3).
// P3: scores via cross-lane reduce over dd lanes; softmax via shfl 16/32; att -> LDS (4KB).
// P4: vv = nx @ Wv (reuse acc regs); ctx = att . vv via 4 fma + shfl reduce; store.
__global__ __launch_bounds__(256, 4)
void k_attn(const unsigned short* srcp, const unsigned short* qb, const int* inds,
            const float* s_pts, const float* q_pts, const float* W_pos, const float* b_pos,
            const unsigned short* wTkv, const float* bv, unsigned short* ctx)
{
    __shared__ alignas(16) unsigned short nx[64 * 256];   // 32 KB, XOR-swizzled rows
    __shared__ alignas(16) float att_lds[4 * 16 * 16];    // 4 KB [q][h][k]
    __shared__ alignas(16) float dist_lds[64];            // dist^2 (scaled by 1/16)
    const int tid = threadIdx.x, wave = tid >> 6, lane = tid & 63;
    const int qbase = blockIdx.x * 4;
    const int l15 = lane & 15, lg = lane >> 4;

    // ---- P1: gather + positional encoding ----
    {
        int r = tid >> 2, sub = tid & 3;          // row 0..63, 64-col chunk
        int qi = qbase + (r >> 4);
        int bb = qi >> 12;                        // / NQ
        int k = r & 15;
        int raw = inds[((size_t)qi << 4) + k];
        int idx = raw % (NS + 1); if (idx < 0) idx += NS + 1;
        float px = q_pts[(size_t)qi * 3], py = q_pts[(size_t)qi * 3 + 1], pz = q_pts[(size_t)qi * 3 + 2];
        bool shadow = (idx == NS);
        float sx, sy, sz;
        const unsigned short* srow = srcp;
        if (shadow) { sx = sy = sz = 1e6f; }
        else {
            const float* sp = s_pts + ((size_t)bb * NS + idx) * 3;
            sx = sp[0]; sy = sp[1]; sz = sp[2];
            srow = srcp + ((size_t)bb * NS + idx) * 256;
        }
        float tx = (sx - px) * 0.25f, ty = (sy - py) * 0.25f, tz = (sz - pz) * 0.25f;
        if (sub == 0) dist_lds[r] = tx * tx + ty * ty + tz * tz;   // >1 <=> dist>RADIUS
        const int c0 = sub * 64;
        for (int cc = 0; cc < 64; cc += 8) {
            short8 sv = {0, 0, 0, 0, 0, 0, 0, 0};
            if (!shadow) sv = *(const short8*)(srow + c0 + cc);
            short8 vals;
            #pragma unroll
            for (int j = 0; j < 8; ++j) {
                int c = c0 + cc + j;
                float pe;
                if (c == 0) pe = tx;
                else if (c == 1) pe = ty;
                else if (c == 2) pe = tz;
                else {
                    int jj = c - 3;
                    float rev = fmaf(tx, W_pos[jj],
                                fmaf(ty, W_pos[253 + jj],
                                fmaf(tz, W_pos[506 + jj], b_pos[jj] * INV2PI)));
                    rev -= floorf(rev);
                    pe = __builtin_amdgcn_cosf(rev);
                }
                float sval = shadow ? 0.f : b2f((unsigned short)sv[j]);
                vals[j] = (short)f2b(sval + pe);
            }
            int byte = (c0 + cc) * 2;
            *(short8*)((char*)nx + r * 512 + (byte ^ ((r & 7) << 4)))= vals;
        }
    }
    __syncthreads();   // the ONLY block-wide barrier

    const int wn = wave * 64;   // this wave's 64 output cols = heads 4w..4w+3
    floatx4 acc[4][4];

    // ---- P2: kk = nx @ Wk (pass 0) ----
    #pragma unroll
    for (int mf = 0; mf < 4; ++mf)
        #pragma unroll
        for (int nf = 0; nf < 4; ++nf) acc[mf][nf] = floatx4{0.f, 0.f, 0.f, 0.f};

    for (int kt = 0; kt < 8; ++kt) {
        short8 bfr[4], afr[4];
        #pragma unroll
        for (int nf = 0; nf < 4; ++nf) {
            int nn = wn + nf * 16 + l15;
            bfr[nf] = *(const short8*)((const char*)wTkv + (size_t)nn * 512 + kt * 64 + (lg << 4));
        }
        #pragma unroll
        for (int mf = 0; mf < 4; ++mf) {
            int rr = mf * 16 + l15;
            afr[mf] = *(const short8*)((const char*)nx + rr * 512 + ((kt * 64 + (lg << 4)) ^ ((rr & 7) << 4)));
        }
        #pragma unroll
        for (int mf = 0; mf < 4; ++mf)
            #pragma unroll
            for (int nf = 0; nf < 4; ++nf)
                acc[mf][nf] = __builtin_amdgcn_mfma_f32_16x16x32_bf16(afr[mf], bfr[nf], acc[mf][nf], 0, 0, 0);
    }

    // ---- P3: scores + softmax (in-register) ----
    // acc[mf][nf][r] = kk[row = mf*16 + lg*4 + r][col = nf*16 + l15]
    //   => query q=mf, neighbor k=lg*4+r, head h=4*wave+nf, dim dd=l15
    {
        float qv[4][4];
        #pragma unroll
        for (int mf = 0; mf < 4; ++mf)
            #pragma unroll
            for (int nf = 0; nf < 4; ++nf)
                qv[mf][nf] = b2f(qb[(size_t)(qbase + mf) * 256 + (wave * 4 + nf) * 16 + l15]);
        #pragma unroll
        for (int mf = 0; mf < 4; ++mf) {
            float4 d4 = *(const float4*)&dist_lds[mf * 16 + lg * 4];   // broadcast read
            float dd4[4] = {d4.x, d4.y, d4.z, d4.w};
            #pragma unroll
            for (int nf = 0; nf < 4; ++nf) {
                float s[4];
                #pragma unroll
                for (int r = 0; r < 4; ++r) s[r] = acc[mf][nf][r] * qv[mf][nf];
                #pragma unroll
                for (int t = 1; t <= 8; t <<= 1)
                    #pragma unroll
                    for (int r = 0; r < 4; ++r) s[r] += __shfl_xor(s[r], t);
                // s[r] now = raw dot over all 16 dd, replicated across the 16-lane group
                #pragma unroll
                for (int r = 0; r < 4; ++r)
                    s[r] = (dd4[r] > 1.0f) ? -1e9f : s[r] * 0.25f;
                float m = fmaxf(fmaxf(s[0], s[1]), fmaxf(s[2], s[3]));
                m = fmaxf(m, __shfl_xor(m, 16));
                m = fmaxf(m, __shfl_xor(m, 32));
                float p[4], su = 0.f;
                #pragma unroll
                for (int r = 0; r < 4; ++r) { p[r] = __expf(s[r] - m); su += p[r]; }
                su += __shfl_xor(su, 16);
                su += __shfl_xor(su, 32);
                float inv = __builtin_amdgcn_rcpf(su);
                if (l15 == 0) {
                    float4 a4 = {p[0] * inv, p[1] * inv, p[2] * inv, p[3] * inv};
                    *(float4*)&att_lds[(mf * 16 + wave * 4 + nf) * 16 + lg * 4] = a4;
                }
            }
        }
    }

    // ---- P4: vv = nx @ Wv (reuse acc), then ctx = att . vv ----
    #pragma unroll
    for (int mf = 0; mf < 4; ++mf)
        #pragma unroll
        for (int nf = 0; nf < 4; ++nf) acc[mf][nf] = floatx4{0.f, 0.f, 0.f, 0.f};

    for (int kt = 0; kt < 8; ++kt) {
        short8 bfr[4], afr[4];
        #pragma unroll
        for (int nf = 0; nf < 4; ++nf) {
            int nn = 256 + wn + nf * 16 + l15;      // Wv half of wTkv
            bfr[nf] = *(const short8*)((const char*)wTkv + (size_t)nn * 512 + kt * 64 + (lg << 4));
        }
        #pragma unroll
        for (int mf = 0; mf < 4; ++mf) {
            int rr = mf * 16 + l15;
            afr[mf] = *(const short8*)((const char*)nx + rr * 512 + ((kt * 64 + (lg << 4)) ^ ((rr & 7) << 4)));
        }
        #pragma unroll
        for (int mf = 0; mf < 4; ++mf)
            #pragma unroll
            for (int nf = 0; nf < 4; ++nf)
                acc[mf][nf] = __builtin_amdgcn_mfma_f32_16x16x32_bf16(afr[mf], bfr[nf], acc[mf][nf], 0, 0, 0);
    }

    {
        float bvv[4];
        #pragma unroll
        for (int nf = 0; nf < 4; ++nf) bvv[nf] = bv[(wave * 4 + nf) * 16 + l15];
        #pragma unroll
        for (int mf = 0; mf < 4; ++mf)
            #pragma unroll
            for (int nf = 0; nf < 4; ++nf) {
                float4 a4 = *(const float4*)&att_lds[(mf * 16 + wave * 4 + nf) * 16 + lg * 4];
                float o = a4.x * acc[mf][nf][0];
                o = fmaf(a4.y, acc[mf][nf][1], o);
                o = fmaf(a4.z, acc[mf][nf][2], o);
                o = fmaf(a4.w, acc[mf][nf][3], o);
                o += __shfl_xor(o, 16);
                o += __shfl_xor(o, 32);
                o += bvv[nf];
                if (lane < 16)
                    ctx[(size_t)(qbase + mf) * 256 + (wave * 4 + nf) * 16 + lane] = f2b(o);
            }
    }
}

// ---------------- host launcher ----------------
extern "C" void kernel_launch(void* const* d_in, const int* in_sizes, int n_in,
                              void* d_out, int out_size, void* d_ws, size_t ws_size,
                              hipStream_t stream)
{
    const float* q_pts   = (const float*)d_in[0];
    const float* s_pts   = (const float*)d_in[1];
    const float* src_f   = (const float*)d_in[2];
    const float* query_f = (const float*)d_in[3];
    const float* W_proj  = (const float*)d_in[4];
    const float* b_proj  = (const float*)d_in[5];
    const float* W_pos   = (const float*)d_in[6];
    const float* b_pos   = (const float*)d_in[7];
    const float* ln1_g   = (const float*)d_in[8];
    const float* ln1_b   = (const float*)d_in[9];
    const float* sa_Wv   = (const float*)d_in[10];
    const float* sa_bv   = (const float*)d_in[11];
    const float* sa_Wo   = (const float*)d_in[12];
    const float* sa_bo   = (const float*)d_in[13];
    const float* ln2_g   = (const float*)d_in[14];
    const float* ln2_b   = (const float*)d_in[15];
    const float* ca_Wq   = (const float*)d_in[16];
    const float* ca_bq   = (const float*)d_in[17];
    const float* ca_Wk   = (const float*)d_in[18];
    /* ca_bk = d_in[19] unused: softmax shift-invariant */
    const float* ca_Wv   = (const float*)d_in[20];
    const float* ca_bv   = (const float*)d_in[21];
    const float* ca_Wo   = (const float*)d_in[22];
    const float* ca_bo   = (const float*)d_in[23];
    const float* ln3_g   = (const float*)d_in[24];
    const float* ln3_b   = (const float*)d_in[25];
    const float* W1      = (const float*)d_in[26];
    const float* b1      = (const float*)d_in[27];
    const float* W2      = (const float*)d_in[28];
    const float* b2      = (const float*)d_in[29];
    const int*   inds    = (const int*)d_in[30];

    char* ws = (char*)d_ws;
    size_t off = 0;
    auto alloc = [&](size_t bytes) { char* p = ws + off; off += (bytes + 1023) & ~(size_t)1023; return p; };

    unsigned short* wTproj = (unsigned short*)alloc(256 * 128 * 2);
    unsigned short* wTsaWv = (unsigned short*)alloc(256 * 256 * 2);
    unsigned short* wTsaWo = (unsigned short*)alloc(256 * 256 * 2);
    unsigned short* wTcaWq = (unsigned short*)alloc(256 * 256 * 2);
    unsigned short* wTkv   = (unsigned short*)alloc(512 * 256 * 2);
    unsigned short* wTcaWo = (unsigned short*)alloc(256 * 256 * 2);
    unsigned short* wTW1   = (unsigned short*)alloc(256 * 256 * 2);
    unsigned short* wTW2   = (unsigned short*)alloc(256 * 256 * 2);
    float*          penc0  = (float*)alloc(256 * 4);
    unsigned short* srcb   = (unsigned short*)alloc((size_t)NROW_S * 128 * 2);
    unsigned short* qfb    = (unsigned short*)alloc((size_t)NROW_Q * 128 * 2);
    unsigned short* srcp   = (unsigned short*)alloc((size_t)NROW_S * 256 * 2);
    float*          qx     = (float*)alloc((size_t)NROW_Q * 256 * 4);
    unsigned short* hbuf   = (unsigned short*)alloc((size_t)NROW_Q * 256 * 2);
    unsigned short* tbuf   = (unsigned short*)alloc((size_t)NROW_Q * 256 * 2);
    float*          xbuf   = (float*)alloc((size_t)NROW_Q * 256 * 4);
    unsigned short* qbuf   = (unsigned short*)alloc((size_t)NROW_Q * 256 * 2);
    unsigned short* ctxbuf = (unsigned short*)alloc((size_t)NROW_Q * 256 * 2);
    float*          x2buf  = (float*)alloc((size_t)NROW_Q * 256 * 4);

    dim3 bl16(16, 16);
    k_prep<<<dim3(16, 16, 10), bl16, 0, stream>>>(
        W_proj, sa_Wv, sa_Wo, ca_Wq, ca_Wk, ca_Wv, ca_Wo, W1, W2, b_pos,
        wTproj, wTsaWv, wTsaWo, wTcaWq, wTkv, wTcaWo, wTW1, wTW2, penc0);

    k_cvt<<<1024, 256, 0, stream>>>(src_f, srcb, NROW_S * 128 / 4);
    k_cvt<<<1024, 256, 0, stream>>>(query_f, qfb, NROW_Q * 128 / 4);

    // src_p = src @ W_proj + b_proj  (bf16)
    k_gemm<0><<<dim3(512, 4), 256, 0, stream>>>(srcb, wTproj, b_proj, nullptr, srcp, NROW_S, 256, 128);
    // query_x = query @ W_proj + b_proj + pos_enc(0)  (f32 master)
    k_gemm<2><<<dim3(128, 4), 256, 0, stream>>>(qfb, wTproj, b_proj, penc0, qx, NROW_Q, 256, 128);

    // self-attention block (seq len 1): x = qx + (ln1(qx)@saWv+bv)@saWo+bo
    k_ln<<<4096, 256, 0, stream>>>(qx, ln1_g, ln1_b, hbuf);
    k_gemm<0><<<dim3(128, 4), 256, 0, stream>>>(hbuf, wTsaWv, sa_bv, nullptr, tbuf, NROW_Q, 256, 256);
    k_gemm<3><<<dim3(128, 4), 256, 0, stream>>>(tbuf, wTsaWo, sa_bo, qx, xbuf, NROW_Q, 256, 256);

    // cross-attention
    k_ln<<<4096, 256, 0, stream>>>(xbuf, ln2_g, ln2_b, hbuf);
    k_gemm<0><<<dim3(128, 4), 256, 0, stream>>>(hbuf, wTcaWq, ca_bq, nullptr, qbuf, NROW_Q, 256, 256);
    k_attn<<<4096, 256, 0, stream>>>(srcp, qbuf, inds, s_pts, q_pts, W_pos, b_pos, wTkv, ca_bv, ctxbuf);
    k_gemm<3><<<dim3(128, 4), 256, 0, stream>>>(ctxbuf, wTcaWo, ca_bo, xbuf, x2buf, NROW_Q, 256, 256);

    // feed-forward + nan_to_num -> d_out (f32)
    k_ln<<<4096, 256, 0, stream>>>(x2buf, ln3_g, ln3_b, hbuf);
    k_gemm<1><<<dim3(128, 4), 256, 0, stream>>>(hbuf, wTW1, b1, nullptr, tbuf, NROW_Q, 256, 256);
    k_gemm<4><<<dim3(128, 4), 256, 0, stream>>>(tbuf, wTW2, b2, x2buf, d_out, NROW_Q, 256, 256);

    (void)in_sizes; (void)n_in; (void)out_size; (void)ws_size;
}

// Round 3
// 395.703 us; speedup vs baseline: 1.0360x; 1.0063x over previous
//
#include <hip/hip_runtime.h>
#include <hip/hip_bf16.h>
#include <math.h>
#include <stdint.h>

// ---------------- types & helpers ----------------
typedef __attribute__((ext_vector_type(8))) short short8;   // 8 x bf16 (MFMA A/B frag)
typedef __attribute__((ext_vector_type(4))) float floatx4;  // MFMA C/D frag

#define DEVI __device__ __forceinline__

DEVI float b2f(unsigned short u) {
    union { unsigned int i; float f; } v; v.i = ((unsigned int)u) << 16; return v.f;
}
DEVI unsigned short f2b(float f) {   // RNE f32 -> bf16
    unsigned int x = __float_as_uint(f);
    unsigned int r = (x + 0x7fffu + ((x >> 16) & 1u)) >> 16;
    return (unsigned short)r;
}

// global -> LDS direct (16B per lane). LDS dest must be wave-uniform base + lane*16.
#define GLD16(gp, lp)                                                            \
    __builtin_amdgcn_global_load_lds(                                            \
        (__attribute__((address_space(1))) unsigned int*)(gp),                   \
        (__attribute__((address_space(3))) unsigned int*)(lp), 16, 0, 0)

static constexpr int NQ = 4096, NS = 16384;
static constexpr int NROW_Q = 4 * NQ;   // 16384 query rows
static constexpr int NROW_S = 4 * NS;   // 65536 source rows
static constexpr float INV2PI = 0.15915494309189535f;

// ---------------- prep: transpose weights to bf16 [N][K], penc0 ----------------
__global__ void k_prep(const float* Wproj, const float* saWv, const float* saWo,
                       const float* caWq, const float* caWk, const float* caWv,
                       const float* caWo, const float* W1, const float* W2,
                       const float* b_pos,
                       unsigned short* wTproj, unsigned short* wTsaWv, unsigned short* wTsaWo,
                       unsigned short* wTcaWq, unsigned short* wTkv, unsigned short* wTcaWo,
                       unsigned short* wTW1, unsigned short* wTW2, float* penc0)
{
    int z = blockIdx.z;
    if (z == 9) {   // penc0[c] = pos_enc(0): [0,0,0, cos(b_pos)]
        if (blockIdx.x == 0 && blockIdx.y == 0) {
            int c = threadIdx.y * 16 + threadIdx.x;
            float v = 0.f;
            if (c >= 3) {
                float rev = b_pos[c - 3] * INV2PI;
                rev -= floorf(rev);
                v = __builtin_amdgcn_cosf(rev);
            }
            penc0[c] = v;
        }
        return;
    }
    int n = blockIdx.x * 16 + threadIdx.x;   // output row (orig col)
    int k = blockIdx.y * 16 + threadIdx.y;   // output col (orig row)
    const float* src; unsigned short* dst; int K = 256;
    switch (z) {
        case 0: src = Wproj; dst = wTproj; K = 128; break;
        case 1: src = saWv;  dst = wTsaWv; break;
        case 2: src = saWo;  dst = wTsaWo; break;
        case 3: src = caWq;  dst = wTcaWq; break;
        case 4: src = caWk;  dst = wTkv;   break;
        case 5: src = caWv;  dst = wTkv + 256 * 256; break;
        case 6: src = caWo;  dst = wTcaWo; break;
        case 7: src = W1;    dst = wTW1;   break;
        default: src = W2;   dst = wTW2;   break;
    }
    if (k < K) dst[(size_t)n * K + k] = f2b(src[(size_t)k * 256 + n]);
}

// ---------------- f32 -> bf16 convert ----------------
__global__ void k_cvt(const float* in, unsigned short* out, int n4)
{
    int i = blockIdx.x * blockDim.x + threadIdx.x;
    int stride = gridDim.x * blockDim.x;
    for (; i < n4; i += stride) {
        float4 v = ((const float4*)in)[i];
        unsigned long long p =
              (unsigned long long)f2b(v.x)
            | ((unsigned long long)f2b(v.y) << 16)
            | ((unsigned long long)f2b(v.z) << 32)
            | ((unsigned long long)f2b(v.w) << 48);
        ((unsigned long long*)out)[i] = p;
    }
}

// ---------------- MFMA GEMM: out[M][N] = A[M][K](bf16) @ BT[N][K]^T + epilogue ----------------
// EPI: 0 = bf16 out, +bias            1 = bf16 out, +bias, relu
//      2 = f32 out, +bias +extra[col] 3 = f32 out, +bias +extra[row,col]
//      4 = f32 out, +bias +extra[row,col], nan_to_num
template<int EPI>
__global__ __launch_bounds__(256, 2)
void k_gemm(const unsigned short* A, const unsigned short* BT, const float* bias,
            const float* extra, void* outp, int M, int N, int K)
{
    __shared__ alignas(16) unsigned short lA[128 * 64];  // [128 rows][64 k], swizzled
    __shared__ alignas(16) unsigned short lB[64 * 64];   // [64 rows][64 k], swizzled
    const int tid = threadIdx.x;
    const int wave = tid >> 6, lane = tid & 63;
    const int m0 = blockIdx.x * 128, n0 = blockIdx.y * 64;
    const int wm = (wave >> 1) * 64, wn = (wave & 1) * 32;
    floatx4 acc[4][2] = {};

    for (int kt = 0; kt < K; kt += 64) {
        __syncthreads();
        #pragma unroll
        for (int c = 0; c < 4; ++c) {   // stage A tile 16KB
            int o = (tid + c * 256) * 16;
            int row = o >> 7, inner = o & 127;
            int srk = inner ^ ((row & 7) << 4);
            GLD16((const char*)A + ((size_t)(m0 + row) * K + kt) * 2 + srk, (char*)lA + o);
        }
        #pragma unroll
        for (int c = 0; c < 2; ++c) {   // stage B tile 8KB
            int o = (tid + c * 256) * 16;
            int row = o >> 7, inner = o & 127;
            int srk = inner ^ ((row & 7) << 4);
            GLD16((const char*)BT + ((size_t)(n0 + row) * K + kt) * 2 + srk, (char*)lB + o);
        }
        __syncthreads();
        #pragma unroll
        for (int kc = 0; kc < 2; ++kc) {
            const int kb = kc * 64 + ((lane >> 4) << 4);
            short8 bf[2];
            #pragma unroll
            for (int nf = 0; nf < 2; ++nf) {
                int nn = wn + nf * 16 + (lane & 15);
                bf[nf] = *(const short8*)((const char*)lB + nn * 128 + (kb ^ ((nn & 7) << 4)));
            }
            #pragma unroll
            for (int mf = 0; mf < 4; ++mf) {
                int rr = wm + mf * 16 + (lane & 15);
                short8 af = *(const short8*)((const char*)lA + rr * 128 + (kb ^ ((rr & 7) << 4)));
                acc[mf][0] = __builtin_amdgcn_mfma_f32_16x16x32_bf16(af, bf[0], acc[mf][0], 0, 0, 0);
                acc[mf][1] = __builtin_amdgcn_mfma_f32_16x16x32_bf16(af, bf[1], acc[mf][1], 0, 0, 0);
            }
        }
    }
    #pragma unroll
    for (int mf = 0; mf < 4; ++mf)
        #pragma unroll
        for (int nf = 0; nf < 2; ++nf)
            #pragma unroll
            for (int r = 0; r < 4; ++r) {
                int row = m0 + wm + mf * 16 + ((lane >> 4) << 2) + r;
                int col = n0 + wn + nf * 16 + (lane & 15);
                float v = acc[mf][nf][r] + bias[col];
                if (EPI == 2) v += extra[col];
                if (EPI == 3 || EPI == 4) v += extra[(size_t)row * N + col];
                if (EPI == 1) v = fmaxf(v, 0.f);
                if (EPI == 4) {
                    if (isnan(v)) v = 0.f;
                    else if (isinf(v)) v = v > 0.f ? 3.402823466e38f : -3.402823466e38f;
                }
                if (EPI == 0 || EPI == 1)
                    ((unsigned short*)outp)[(size_t)row * N + col] = f2b(v);
                else
                    ((float*)outp)[(size_t)row * N + col] = v;
            }
}

// ---------------- LayerNorm (f32 in, bf16 out), one wave per 256-row ----------------
__global__ __launch_bounds__(256, 2)
void k_ln(const float* x, const float* g, const float* b, unsigned short* out)
{
    int row = blockIdx.x * 4 + (threadIdx.x >> 6);
    int lane = threadIdx.x & 63;
    const float* xr = x + (size_t)row * 256;
    float4 v = ((const float4*)xr)[lane];
    float s = v.x + v.y + v.z + v.w;
    #pragma unroll
    for (int t = 32; t >= 1; t >>= 1) s += __shfl_xor(s, t, 64);
    float mean = s * (1.f / 256.f);
    float d0 = v.x - mean, d1 = v.y - mean, d2 = v.z - mean, d3 = v.w - mean;
    float q = d0 * d0 + d1 * d1 + d2 * d2 + d3 * d3;
    #pragma unroll
    for (int t = 32; t >= 1; t >>= 1) q += __shfl_xor(q, t, 64);
    float inv = 1.0f / sqrtf(q * (1.f / 256.f) + 1e-5f);
    int c = lane * 4;
    unsigned long long p =
          (unsigned long long)f2b(d0 * inv * g[c] + b[c])
        | ((unsigned long long)f2b(d1 * inv * g[c + 1] + b[c + 1]) << 16)
        | ((unsigned long long)f2b(d2 * inv * g[c + 2] + b[c + 2]) << 32)
        | ((unsigned long long)f2b(d3 * inv * g[c + 3] + b[c + 3]) << 48);
    ((unsigned long long*)(out + (size_t)row * 256))[lane] = p;
}

// ---------------- fused neighbor attention (register-resident, no spill) ----------------
// block = 4 queries (64 neighbor rows), 256 threads (4 waves). 3-4 blocks/CU.
// P1: prefetch-all gather + pos-enc -> nx LDS (bf16, swizzled). ONE barrier.
// P2: kk = nx @ Wk, acc[4][4] in regs; register-lean loop (bfr[4], single af).
// P3: scores via cross-lane reduce over dd lanes; softmax via shfl 16/32; att -> LDS.
// P4: vv = nx @ Wv (reuse acc); ctx = att . vv via 4 fma + shfl reduce; store.
__global__ __launch_bounds__(256, 3)
void k_attn(const unsigned short* srcp, const unsigned short* qb, const int* inds,
            const float* s_pts, const float* q_pts, const float* W_pos, const float* b_pos,
            const unsigned short* wTkv, const float* bv, unsigned short* ctx)
{
    __shared__ alignas(16) unsigned short nx[64 * 256];   // 32 KB, XOR-swizzled rows
    __shared__ alignas(16) float att_lds[4 * 16 * 16];    // 4 KB [q][h][k]
    __shared__ alignas(16) float dist_lds[64];            // (dist/RADIUS)^2
    const int tid = threadIdx.x, wave = tid >> 6, lane = tid & 63;
    const int qbase = blockIdx.x * 4;
    const int l15 = lane & 15, lg = lane >> 4;

    // ---- P1: gather + positional encoding (loads issued first, cos hides latency) ----
    {
        int r = tid >> 2, sub = tid & 3;          // row 0..63, 64-col chunk
        int qi = qbase + (r >> 4);
        int bb = qi >> 12;                        // / NQ
        int k = r & 15;
        int raw = inds[((size_t)qi << 4) + k];
        int idx = raw % (NS + 1); if (idx < 0) idx += NS + 1;
        bool shadow = (idx == NS);
        const int c0 = sub * 64;
        // issue ALL 8 feature loads up-front (shadow rows read row 0, masked later)
        const unsigned short* srow = srcp + ((size_t)bb * NS + (shadow ? 0 : idx)) * 256 + c0;
        short8 sv[8];
        #pragma unroll
        for (int j = 0; j < 8; ++j) sv[j] = *(const short8*)(srow + j * 8);

        float px = q_pts[(size_t)qi * 3], py = q_pts[(size_t)qi * 3 + 1], pz = q_pts[(size_t)qi * 3 + 2];
        float sx, sy, sz;
        if (shadow) { sx = sy = sz = 1e6f; }
        else {
            const float* sp = s_pts + ((size_t)bb * NS + idx) * 3;
            sx = sp[0]; sy = sp[1]; sz = sp[2];
        }
        float tx = (sx - px) * 0.25f, ty = (sy - py) * 0.25f, tz = (sz - pz) * 0.25f;
        if (sub == 0) dist_lds[r] = tx * tx + ty * ty + tz * tz;   // >1 <=> dist>RADIUS

        #pragma unroll
        for (int cc = 0; cc < 64; cc += 8) {
            short8 vals;
            #pragma unroll
            for (int j = 0; j < 8; ++j) {
                int c = c0 + cc + j;
                float pe;
                if (c == 0) pe = tx;
                else if (c == 1) pe = ty;
                else if (c == 2) pe = tz;
                else {
                    int jj = c - 3;
                    float rev = fmaf(tx, W_pos[jj],
                                fmaf(ty, W_pos[253 + jj],
                                fmaf(tz, W_pos[506 + jj], b_pos[jj] * INV2PI)));
                    rev -= floorf(rev);
                    pe = __builtin_amdgcn_cosf(rev);
                }
                float sval = shadow ? 0.f : b2f((unsigned short)sv[cc / 8][j]);
                vals[j] = (short)f2b(sval + pe);
            }
            int byte = (c0 + cc) * 2;
            *(short8*)((char*)nx + r * 512 + (byte ^ ((r & 7) << 4))) = vals;
        }
    }
    __syncthreads();   // the ONLY block-wide barrier

    const int wn = wave * 64;   // this wave's 64 output cols = heads 4w..4w+3
    floatx4 acc[4][4];

    // ---- P2: kk = nx @ Wk ----
    #pragma unroll
    for (int mf = 0; mf < 4; ++mf)
        #pragma unroll
        for (int nf = 0; nf < 4; ++nf) acc[mf][nf] = floatx4{0.f, 0.f, 0.f, 0.f};

    #pragma unroll 2
    for (int kt = 0; kt < 8; ++kt) {
        const int kb = kt * 64 + (lg << 4);
        short8 bfr[4];
        #pragma unroll
        for (int nf = 0; nf < 4; ++nf) {
            int nn = wn + nf * 16 + l15;
            bfr[nf] = *(const short8*)((const char*)wTkv + (size_t)nn * 512 + kt * 64 + (lg << 4));
        }
        #pragma unroll
        for (int mf = 0; mf < 4; ++mf) {
            int rr = mf * 16 + l15;
            short8 af = *(const short8*)((const char*)nx + rr * 512 + (kb ^ ((rr & 7) << 4)));
            #pragma unroll
            for (int nf = 0; nf < 4; ++nf)
                acc[mf][nf] = __builtin_amdgcn_mfma_f32_16x16x32_bf16(af, bfr[nf], acc[mf][nf], 0, 0, 0);
        }
    }

    // ---- P3: scores + softmax (in-register) ----
    // acc[mf][nf][r] = kk[row = mf*16 + lg*4 + r][col = nf*16 + l15]
    //   => query q=mf, neighbor k=lg*4+r, head h=4*wave+nf, dim dd=l15
    {
        #pragma unroll
        for (int mf = 0; mf < 4; ++mf) {
            float4 d4 = *(const float4*)&dist_lds[mf * 16 + lg * 4];   // broadcast read
            float dd4[4] = {d4.x, d4.y, d4.z, d4.w};
            #pragma unroll
            for (int nf = 0; nf < 4; ++nf) {
                float qv = b2f(qb[(size_t)(qbase + mf) * 256 + (wave * 4 + nf) * 16 + l15]);
                float s[4];
                #pragma unroll
                for (int r = 0; r < 4; ++r) s[r] = acc[mf][nf][r] * qv;
                #pragma unroll
                for (int t = 1; t <= 8; t <<= 1)
                    #pragma unroll
                    for (int r = 0; r < 4; ++r) s[r] += __shfl_xor(s[r], t);
                // s[r] now = raw dot over all 16 dd, replicated across the 16-lane group
                #pragma unroll
                for (int r = 0; r < 4; ++r)
                    s[r] = (dd4[r] > 1.0f) ? -1e9f : s[r] * 0.25f;
                float m = fmaxf(fmaxf(s[0], s[1]), fmaxf(s[2], s[3]));
                m = fmaxf(m, __shfl_xor(m, 16));
                m = fmaxf(m, __shfl_xor(m, 32));
                float p[4], su = 0.f;
                #pragma unroll
                for (int r = 0; r < 4; ++r) { p[r] = __expf(s[r] - m); su += p[r]; }
                su += __shfl_xor(su, 16);
                su += __shfl_xor(su, 32);
                float inv = __builtin_amdgcn_rcpf(su);
                if (l15 == 0) {
                    float4 a4 = {p[0] * inv, p[1] * inv, p[2] * inv, p[3] * inv};
                    *(float4*)&att_lds[(mf * 16 + wave * 4 + nf) * 16 + lg * 4] = a4;
                }
            }
        }
    }

    // ---- P4: vv = nx @ Wv (reuse acc), then ctx = att . vv ----
    #pragma unroll
    for (int mf = 0; mf < 4; ++mf)
        #pragma unroll
        for (int nf = 0; nf < 4; ++nf) acc[mf][nf] = floatx4{0.f, 0.f, 0.f, 0.f};

    #pragma unroll 2
    for (int kt = 0; kt < 8; ++kt) {
        const int kb = kt * 64 + (lg << 4);
        short8 bfr[4];
        #pragma unroll
        for (int nf = 0; nf < 4; ++nf) {
            int nn = 256 + wn + nf * 16 + l15;      // Wv half of wTkv
            bfr[nf] = *(const short8*)((const char*)wTkv + (size_t)nn * 512 + kt * 64 + (lg << 4));
        }
        #pragma unroll
        for (int mf = 0; mf < 4; ++mf) {
            int rr = mf * 16 + l15;
            short8 af = *(const short8*)((const char*)nx + rr * 512 + (kb ^ ((rr & 7) << 4)));
            #pragma unroll
            for (int nf = 0; nf < 4; ++nf)
                acc[mf][nf] = __builtin_amdgcn_mfma_f32_16x16x32_bf16(af, bfr[nf], acc[mf][nf], 0, 0, 0);
        }
    }

    {
        #pragma unroll
        for (int mf = 0; mf < 4; ++mf)
            #pragma unroll
            for (int nf = 0; nf < 4; ++nf) {
                float4 a4 = *(const float4*)&att_lds[(mf * 16 + wave * 4 + nf) * 16 + lg * 4];
                float o = a4.x * acc[mf][nf][0];
                o = fmaf(a4.y, acc[mf][nf][1], o);
                o = fmaf(a4.z, acc[mf][nf][2], o);
                o = fmaf(a4.w, acc[mf][nf][3], o);
                o += __shfl_xor(o, 16);
                o += __shfl_xor(o, 32);
                o += bv[(wave * 4 + nf) * 16 + l15];
                if (lane < 16)
                    ctx[(size_t)(qbase + mf) * 256 + (wave * 4 + nf) * 16 + lane] = f2b(o);
            }
    }
}

// ---------------- host launcher ----------------
extern "C" void kernel_launch(void* const* d_in, const int* in_sizes, int n_in,
                              void* d_out, int out_size, void* d_ws, size_t ws_size,
                              hipStream_t stream)
{
    const float* q_pts   = (const float*)d_in[0];
    const float* s_pts   = (const float*)d_in[1];
    const float* src_f   = (const float*)d_in[2];
    const float* query_f = (const float*)d_in[3];
    const float* W_proj  = (const float*)d_in[4];
    const float* b_proj  = (const float*)d_in[5];
    const float* W_pos   = (const float*)d_in[6];
    const float* b_pos   = (const float*)d_in[7];
    const float* ln1_g   = (const float*)d_in[8];
    const float* ln1_b   = (const float*)d_in[9];
    const float* sa_Wv   = (const float*)d_in[10];
    const float* sa_bv   = (const float*)d_in[11];
    const float* sa_Wo   = (const float*)d_in[12];
    const float* sa_bo   = (const float*)d_in[13];
    const float* ln2_g   = (const float*)d_in[14];
    const float* ln2_b   = (const float*)d_in[15];
    const float* ca_Wq   = (const float*)d_in[16];
    const float* ca_bq   = (const float*)d_in[17];
    const float* ca_Wk   = (const float*)d_in[18];
    /* ca_bk = d_in[19] unused: softmax shift-invariant */
    const float* ca_Wv   = (const float*)d_in[20];
    const float* ca_bv   = (const float*)d_in[21];
    const float* ca_Wo   = (const float*)d_in[22];
    const float* ca_bo   = (const float*)d_in[23];
    const float* ln3_g   = (const float*)d_in[24];
    const float* ln3_b   = (const float*)d_in[25];
    const float* W1      = (const float*)d_in[26];
    const float* b1      = (const float*)d_in[27];
    const float* W2      = (const float*)d_in[28];
    const float* b2      = (const float*)d_in[29];
    const int*   inds    = (const int*)d_in[30];

    char* ws = (char*)d_ws;
    size_t off = 0;
    auto alloc = [&](size_t bytes) { char* p = ws + off; off += (bytes + 1023) & ~(size_t)1023; return p; };

    unsigned short* wTproj = (unsigned short*)alloc(256 * 128 * 2);
    unsigned short* wTsaWv = (unsigned short*)alloc(256 * 256 * 2);
    unsigned short* wTsaWo = (unsigned short*)alloc(256 * 256 * 2);
    unsigned short* wTcaWq = (unsigned short*)alloc(256 * 256 * 2);
    unsigned short* wTkv   = (unsigned short*)alloc(512 * 256 * 2);
    unsigned short* wTcaWo = (unsigned short*)alloc(256 * 256 * 2);
    unsigned short* wTW1   = (unsigned short*)alloc(256 * 256 * 2);
    unsigned short* wTW2   = (unsigned short*)alloc(256 * 256 * 2);
    float*          penc0  = (float*)alloc(256 * 4);
    unsigned short* srcb   = (unsigned short*)alloc((size_t)NROW_S * 128 * 2);
    unsigned short* qfb    = (unsigned short*)alloc((size_t)NROW_Q * 128 * 2);
    unsigned short* srcp   = (unsigned short*)alloc((size_t)NROW_S * 256 * 2);
    float*          qx     = (float*)alloc((size_t)NROW_Q * 256 * 4);
    unsigned short* hbuf   = (unsigned short*)alloc((size_t)NROW_Q * 256 * 2);
    unsigned short* tbuf   = (unsigned short*)alloc((size_t)NROW_Q * 256 * 2);
    float*          xbuf   = (float*)alloc((size_t)NROW_Q * 256 * 4);
    unsigned short* qbuf   = (unsigned short*)alloc((size_t)NROW_Q * 256 * 2);
    unsigned short* ctxbuf = (unsigned short*)alloc((size_t)NROW_Q * 256 * 2);
    float*          x2buf  = (float*)alloc((size_t)NROW_Q * 256 * 4);

    dim3 bl16(16, 16);
    k_prep<<<dim3(16, 16, 10), bl16, 0, stream>>>(
        W_proj, sa_Wv, sa_Wo, ca_Wq, ca_Wk, ca_Wv, ca_Wo, W1, W2, b_pos,
        wTproj, wTsaWv, wTsaWo, wTcaWq, wTkv, wTcaWo, wTW1, wTW2, penc0);

    k_cvt<<<1024, 256, 0, stream>>>(src_f, srcb, NROW_S * 128 / 4);
    k_cvt<<<1024, 256, 0, stream>>>(query_f, qfb, NROW_Q * 128 / 4);

    // src_p = src @ W_proj + b_proj  (bf16)
    k_gemm<0><<<dim3(512, 4), 256, 0, stream>>>(srcb, wTproj, b_proj, nullptr, srcp, NROW_S, 256, 128);
    // query_x = query @ W_proj + b_proj + pos_enc(0)  (f32 master)
    k_gemm<2><<<dim3(128, 4), 256, 0, stream>>>(qfb, wTproj, b_proj, penc0, qx, NROW_Q, 256, 128);

    // self-attention block (seq len 1): x = qx + (ln1(qx)@saWv+bv)@saWo+bo
    k_ln<<<4096, 256, 0, stream>>>(qx, ln1_g, ln1_b, hbuf);
    k_gemm<0><<<dim3(128, 4), 256, 0, stream>>>(hbuf, wTsaWv, sa_bv, nullptr, tbuf, NROW_Q, 256, 256);
    k_gemm<3><<<dim3(128, 4), 256, 0, stream>>>(tbuf, wTsaWo, sa_bo, qx, xbuf, NROW_Q, 256, 256);

    // cross-attention
    k_ln<<<4096, 256, 0, stream>>>(xbuf, ln2_g, ln2_b, hbuf);
    k_gemm<0><<<dim3(128, 4), 256, 0, stream>>>(hbuf, wTcaWq, ca_bq, nullptr, qbuf, NROW_Q, 256, 256);
    k_attn<<<4096, 256, 0, stream>>>(srcp, qbuf, inds, s_pts, q_pts, W_pos, b_pos, wTkv, ca_bv, ctxbuf);
    k_gemm<3><<<dim3(128, 4), 256, 0, stream>>>(ctxbuf, wTcaWo, ca_bo, xbuf, x2buf, NROW_Q, 256, 256);

    // feed-forward + nan_to_num -> d_out (f32)
    k_ln<<<4096, 256, 0, stream>>>(x2buf, ln3_g, ln3_b, hbuf);
    k_gemm<1><<<dim3(128, 4), 256, 0, stream>>>(hbuf, wTW1, b1, nullptr, tbuf, NROW_Q, 256, 256);
    k_gemm<4><<<dim3(128, 4), 256, 0, stream>>>(tbuf, wTW2, b2, x2buf, d_out, NROW_Q, 256, 256);

    (void)in_sizes; (void)n_in; (void)out_size; (void)ws_size;
}